// Round 9
// baseline (438.480 us; speedup 1.0000x reference)
//
#include <hip/hip_runtime.h>
#include <math.h>

#define NCLS 20
#define IGNORE_IDX 255
#define LOG2E 1.4426950408889634f
#define NTHR 640   // 10 waves: wave w owns classes w and w+10
#define TILEV 512  // voxels per LDS tile
#define NBLK 768   // 3 blocks/CU (LDS- and thread-limited), grid-stride tiles
#define NSLOT 32   // global partial-sum slots

typedef float v4f __attribute__((ext_vector_type(4)));
typedef int v4i __attribute__((ext_vector_type(4)));

__device__ __forceinline__ float wave_reduce(float v) {
#pragma unroll
  for (int off = 32; off > 0; off >>= 1) v += __shfl_xor(v, off, 64);
  return v;
}

__device__ __forceinline__ float neg_log_clamped(float x, bool cond) {
  if (!cond) return 0.0f;
  float xs = fmaxf(x, 1e-38f);
  return fminf(-logf(xs), 100.0f);
}

// ws columns: [0..19] sum_p, [20..39] nominator, [40..59] ct_count.
//
// r9 design notes — the untested quadrant (clean regs x high occupancy):
//  - Evidence r0-r8: dirty-regs kernels (AGPR spill) cap at 1.3-1.8 TB/s at
//    ANY occupancy; the one clean-regs kernel (r4) had only 11 waves/CU;
//    gload_lds (r5/r8) is 0.68 TB/s regardless of vmcnt discipline. The two
//    known-fast kernels (m13 copy 6.3 TB/s, fillBuffer 6.75) are BOTH
//    clean-regs + ~full occupancy + load-consumed-immediately.
//  - Class-parallel waves: wave w streams classes {w, w+10} in 2KB
//    contiguous runs (copy-like), exp -> ds_write e-tile + ds_add z-tile.
//    No per-class register arrays ANYWHERE -> ~50 transient VGPRs.
//  - Swizzled LDS slot = j*128+i*64+lane -> bank = lane%32 for every
//    ds op (2-way = free, m136). z gets 20 fire-and-forget adds/voxel.
//  - Pass B: p = es[c][s]*rcp(z[s]); sum_p/nom/cnt live in 6 SCALAR regs
//    per thread across all tiles; one wave-reduce + 6 global atomics per
//    wave at kernel end. Per-class reduction cost ~0.
//  - LDS 44KB -> 3 blocks/CU; 640 thr x 3 = 1920/2048 threads -> 30
//    waves/CU (94%), thread-capped not VGPR-capped. Plain launch_bounds
//    (no min-waves arg: proven AGPR-offload trigger in r2/r7).
__global__ __launch_bounds__(NTHR) void pass1(const float* __restrict__ pred,
                                              const int* __restrict__ target,
                                              float* __restrict__ ws, int N) {
  __shared__ float es[NCLS][TILEV];  // 40 KB, slot-swizzled
  __shared__ float zz[TILEV];        // 2 KB softmax denominators
  __shared__ int ts[TILEV];          // 2 KB staged targets
  const int tid = threadIdx.x;
  const int wid = tid >> 6;
  const int lane = tid & 63;

  float sp[2] = {0.0f, 0.0f}, nom[2] = {0.0f, 0.0f}, cnt[2] = {0.0f, 0.0f};

  const long long step = (long long)NBLK * TILEV;
  for (long long t0 = (long long)blockIdx.x * TILEV; t0 < N; t0 += step) {
    // zero z; stage targets at swizzled slots (slot(o) = (o&3)*128 + o>>2)
    if (tid < TILEV) zz[tid] = 0.0f;
    if (tid < TILEV / 4) {
      const long long g = t0 + tid * 4;
      const long long ga = g > (long long)N - 4 ? (long long)N - 4 : g;
      const v4i t4 = *reinterpret_cast<const v4i*>(target + ga);
#pragma unroll
      for (int j = 0; j < 4; ++j)
        ts[j * 128 + tid] = (g + j < N) ? t4[j] : IGNORE_IDX;
    }
    __syncthreads();  // B1: z zeroed, t staged

    // ---- pass A: stream 2 planes, exp, scatter to LDS (all banks free)
#pragma unroll
    for (int pi = 0; pi < 2; ++pi) {
      const int c = wid + pi * 10;
#pragma unroll
      for (int i = 0; i < 2; ++i) {
        const long long g = t0 + i * 256 + lane * 4;
        const long long ga = g > (long long)N - 4 ? (long long)N - 4 : g;
        const v4f x = *reinterpret_cast<const v4f*>(pred + (size_t)c * N + ga);
#pragma unroll
        for (int j = 0; j < 4; ++j) {
          float e = __builtin_amdgcn_exp2f(fminf(x[j], 80.0f) * LOG2E);
          if (g + j >= N) e = 0.0f;  // tail: contribute nothing
          const int s = j * 128 + i * 64 + lane;
          es[c][s] = e;
          atomicAdd(&zz[s], e);  // fire-and-forget ds_add_f32
        }
      }
    }
    __syncthreads();  // B2: z complete, e complete

    // ---- pass B: shared per-voxel values once, then 2 class-sweeps
    float rz[2][4];
    int tv[2][4];
#pragma unroll
    for (int i = 0; i < 2; ++i)
#pragma unroll
      for (int j = 0; j < 4; ++j) {
        const int s = j * 128 + i * 64 + lane;
        rz[i][j] = __builtin_amdgcn_rcpf(zz[s]);
        tv[i][j] = ts[s];
      }
#pragma unroll
    for (int pi = 0; pi < 2; ++pi) {
      const int c = wid + pi * 10;
#pragma unroll
      for (int i = 0; i < 2; ++i)
#pragma unroll
        for (int j = 0; j < 4; ++j) {
          const int s = j * 128 + i * 64 + lane;
          const float p = es[c][s] * rz[i][j];
          // tail slots: e=0 but rz may be inf -> p NaN; tv==255 deselects.
          sp[pi] += (tv[i][j] != IGNORE_IDX) ? p : 0.0f;
          if (tv[i][j] == c) {
            nom[pi] += p;
            cnt[pi] += 1.0f;
          }
        }
    }
    __syncthreads();  // B3: reads done; next iter may overwrite tiles
  }

  // ---- flush: 6 wave-reduces, lane0 -> relaxed global atomics (pass2 is a
  // separate dispatch; kernel boundary provides visibility).
#pragma unroll
  for (int pi = 0; pi < 2; ++pi) {
    const int c = wid + pi * 10;
    const float s = wave_reduce(sp[pi]);
    const float nm = wave_reduce(nom[pi]);
    const float ct = wave_reduce(cnt[pi]);
    if (lane == 0) {
      float* row = ws + (size_t)(blockIdx.x & (NSLOT - 1)) * 64;
      atomicAdd(row + c, s);
      atomicAdd(row + NCLS + c, nm);
      atomicAdd(row + 2 * NCLS + c, ct);
    }
  }
}

__global__ __launch_bounds__(64) void pass2(const float* __restrict__ ws,
                                            float* __restrict__ out) {
  __shared__ float s[64];
  const int lane = threadIdx.x;
  float a = 0.0f;
#pragma unroll
  for (int r = 0; r < NSLOT; ++r) a += ws[r * 64 + lane];  // 32 indep loads

  // n_masked = sum of ct_count columns (lanes 40..59), uniform collective
  const float n_masked =
      wave_reduce((lane >= 2 * NCLS && lane < 3 * NCLS) ? a : 0.0f);

  // LDS bounce for per-class gather — NO divergent cross-lane ops
  s[lane] = a;
  __syncthreads();

  float loss = 0.0f, validf = 0.0f;
  if (lane < NCLS) {
    const float sump = s[lane];
    const float nm = s[NCLS + lane];
    const float ct = s[2 * NCLS + lane];
    const bool valid = ct > 0.0f;
    const float prec = nm / fmaxf(sump, 1e-38f);
    const float rec = nm / fmaxf(ct, 1.0f);
    const float negc = n_masked - ct;
    const float specn = n_masked - sump - ct + nm;
    const float spec = specn / fmaxf(negc, 1.0f);
    loss = neg_log_clamped(prec, valid && (sump > 0.0f)) +
           neg_log_clamped(rec, valid) +
           neg_log_clamped(spec, valid && (negc > 0.0f));
    validf = valid ? 1.0f : 0.0f;
  }
  loss = wave_reduce(loss);  // uniform: all 64 lanes participate
  validf = wave_reduce(validf);
  if (lane == 0) out[0] = loss / validf;
}

extern "C" void kernel_launch(void* const* d_in, const int* in_sizes, int n_in,
                              void* d_out, int out_size, void* d_ws, size_t ws_size,
                              hipStream_t stream) {
  const float* pred = (const float*)d_in[0];
  const int* target = (const int*)d_in[1];
  const int N = in_sizes[1];  // voxel count; C = in_sizes[0]/N = 20

  hipMemsetAsync(d_ws, 0, NSLOT * 64 * sizeof(float), stream);
  pass1<<<NBLK, NTHR, 0, stream>>>(pred, target, (float*)d_ws, N);
  pass2<<<1, 64, 0, stream>>>((const float*)d_ws, (float*)d_out);
}